// Round 11
// baseline (1188.321 us; speedup 1.0000x reference)
//
#include <hip/hip_runtime.h>

// GCN: N=100000, E=1600000, C=128/128/64.
// R2: single-stream CSR fill. R4: gemm unroll/VGPR fix. R5: nt scatter FAILED.
// R7: rank-from-count (atomic-free fill). R8: gather ILP -> only -4%: random
//     row gather plateaus ~4-5TB/s logical. R9: bf16 gather tables -> 688us.
// R10: feature-chunked gather passes (slice L2-resident); compile error on
//     nt-store of HIP float4 -> R11: use clang ext_vector_type alias.
//     CONTROL: k_aggregate<64> stays monolithic for within-profile comparison.

typedef float f32x4 __attribute__((ext_vector_type(4)));

__device__ __forceinline__ int edge_at(const int* __restrict__ ei, long long idx, int is32) {
    return is32 ? ei[idx] : ei[2 * idx];
}

__device__ __forceinline__ unsigned short f2bf(float f) {
    unsigned int u = __float_as_uint(f);
    u += 0x7FFFu + ((u >> 16) & 1u);
    return (unsigned short)(u >> 16);
}
__device__ __forceinline__ float bf2f(unsigned short h) {
    return __uint_as_float(((unsigned int)h) << 16);
}

// Wave-reduced detect: OR odd words locally, <=1 atomic per wave.
__global__ __launch_bounds__(256) void k_detect(const int4* __restrict__ ei4, int nchunks,
                                                int* __restrict__ flag) {
    int acc = 0;
    for (int i = blockIdx.x * 256 + threadIdx.x; i < nchunks; i += gridDim.x * 256) {
        int4 v = ei4[i];
        acc |= v.y | v.w;
    }
    if (__any(acc != 0)) {
        if ((threadIdx.x & 63) == 0) atomicOr(flag, 1);
    }
}

// Count degrees AND record per-edge rank among same-dst edges.
__global__ __launch_bounds__(256) void k_count(const int* __restrict__ ei, int E, int* __restrict__ cnt,
                                               int* __restrict__ rank, const int* __restrict__ flag) {
    int is32 = *flag;
    int e = blockIdx.x * 256 + threadIdx.x;
    if (e < E) {
        int d = edge_at(ei, (long long)E + e, is32);
        rank[e] = atomicAdd(&cnt[d], 1);
    }
}

__global__ __launch_bounds__(256) void k_scan_local(const int* __restrict__ cnt, int N,
                                                    int* __restrict__ offs, int* __restrict__ bsums) {
    __shared__ int wsum[4];
    int t = threadIdx.x;
    int lane = t & 63, wid = t >> 6;
    int gbase = blockIdx.x * 1024 + t * 4;
    int v0 = 0, v1 = 0, v2 = 0, v3 = 0;
    if (gbase + 0 < N) v0 = cnt[gbase + 0];
    if (gbase + 1 < N) v1 = cnt[gbase + 1];
    if (gbase + 2 < N) v2 = cnt[gbase + 2];
    if (gbase + 3 < N) v3 = cnt[gbase + 3];
    int tot = v0 + v1 + v2 + v3;
    int x = tot;
#pragma unroll
    for (int d = 1; d < 64; d <<= 1) {
        int y = __shfl_up(x, d);
        if (lane >= d) x += y;
    }
    if (lane == 63) wsum[wid] = x;
    __syncthreads();
    int wbase = 0;
#pragma unroll
    for (int w = 0; w < 4; w++)
        if (w < wid) wbase += wsum[w];
    int ex = wbase + x - tot;
    if (gbase + 0 < N) offs[gbase + 0] = ex;
    if (gbase + 1 < N) offs[gbase + 1] = ex + v0;
    if (gbase + 2 < N) offs[gbase + 2] = ex + v0 + v1;
    if (gbase + 3 < N) offs[gbase + 3] = ex + v0 + v1 + v2;
    if (t == 255) bsums[blockIdx.x] = wbase + x;
}

__global__ void k_scan_bsums(int* __restrict__ bsums, int nb) {
    int run = 0;
    for (int i = 0; i < nb; i++) {
        int v = bsums[i];
        bsums[i] = run;
        run += v;
    }
}

__global__ __launch_bounds__(256) void k_scan_add(int* __restrict__ offs, const int* __restrict__ bsums,
                                                  const int* __restrict__ cnt, float* __restrict__ dinv, int N) {
    int i = blockIdx.x * 256 + threadIdx.x;
    if (i < N) {
        offs[i] += bsums[i >> 10];
        dinv[i] = rsqrtf((float)(cnt[i] + 1));
    }
}

// Atomic-free scatter: pos = offs_excl[d] + rank[e].
__global__ __launch_bounds__(256) void k_fill(const int* __restrict__ ei, int E,
                                              const int* __restrict__ offs, const int* __restrict__ rank,
                                              int* __restrict__ csr_src, const int* __restrict__ flag) {
    int is32 = *flag;
    int e = blockIdx.x * 256 + threadIdx.x;
    if (e < E) {
        int s = edge_at(ei, e, is32);
        int d = edge_at(ei, (long long)E + e, is32);
        int pos = offs[d] + rank[e];
        csr_src[pos] = s;
    }
}

// -------- dense GEMM: Ybf16 = f2bf( rscale? ⊙ (X @ W) ) --------
template <int CIN, int COUT, bool RSCALE>
__global__ __launch_bounds__(256, 4) void k_gemm(const float* __restrict__ X, const float* __restrict__ W,
                                                 unsigned short* __restrict__ Y, int N,
                                                 const float* __restrict__ rscale) {
    constexpr int CT = COUT / 4;
    constexpr int RG = 256 / CT;
    constexpr int RPT = 64 / RG;
    constexpr int LDX = CIN + 4;
    __shared__ float xs[64 * LDX];
    int t = threadIdx.x;
    int r0 = blockIdx.x * 64;
    int nrows = (N - r0 < 64) ? (N - r0) : 64;
    for (int c = t; c < 64 * (CIN / 4); c += 256) {
        int row = c / (CIN / 4);
        int col = (c % (CIN / 4)) * 4;
        float4 v = make_float4(0.f, 0.f, 0.f, 0.f);
        if (row < nrows) v = *(const float4*)&X[(size_t)(r0 + row) * CIN + col];
        *(float4*)&xs[row * LDX + col] = v;
    }
    __syncthreads();

    int ct = t % CT, rg = t / CT;
    float4 acc[RPT];
#pragma unroll
    for (int j = 0; j < RPT; j++) acc[j] = make_float4(0.f, 0.f, 0.f, 0.f);
    const float* wp = W + ct * 4;
#pragma unroll 2
    for (int k = 0; k < CIN; k += 4) {
        float4 w0 = *(const float4*)&wp[(size_t)(k + 0) * COUT];
        float4 w1 = *(const float4*)&wp[(size_t)(k + 1) * COUT];
        float4 w2 = *(const float4*)&wp[(size_t)(k + 2) * COUT];
        float4 w3 = *(const float4*)&wp[(size_t)(k + 3) * COUT];
#pragma unroll
        for (int j = 0; j < RPT; j++) {
            float4 a = *(const float4*)&xs[(rg * RPT + j) * LDX + k];
            acc[j].x += a.x * w0.x + a.y * w1.x + a.z * w2.x + a.w * w3.x;
            acc[j].y += a.x * w0.y + a.y * w1.y + a.z * w2.y + a.w * w3.y;
            acc[j].z += a.x * w0.z + a.y * w1.z + a.z * w2.z + a.w * w3.z;
            acc[j].w += a.x * w0.w + a.y * w1.w + a.z * w2.w + a.w * w3.w;
        }
    }
#pragma unroll
    for (int j = 0; j < RPT; j++) {
        int row = r0 + rg * RPT + j;
        if (row < N) {
            float4 a = acc[j];
            if constexpr (RSCALE) {
                float s = rscale[row];
                a.x *= s; a.y *= s; a.z *= s; a.w *= s;
            }
            ushort4 o;
            o.x = f2bf(a.x); o.y = f2bf(a.y); o.z = f2bf(a.z); o.w = f2bf(a.w);
            *(ushort4*)&Y[(size_t)row * COUT + ct * 4] = o;
        }
    }
}

// ------- chunked aggregation (C=128, 16-col slice per launch) -------
// 4 lanes per node, lane li owns cols [ch*16+li*4, +4). Table slice 3.2MB ->
// L2-resident per XCD. Columns independent -> each pass complete (incl. relu).
template <bool RELU>
__global__ __launch_bounds__(256) void k_agg16(const unsigned short* __restrict__ T,
                                               const int* __restrict__ offs,
                                               const int* __restrict__ cnt, const int* __restrict__ csr_src,
                                               const float* __restrict__ dinv,
                                               const float* __restrict__ bias, float* __restrict__ H,
                                               int N, int ch) {
    int li = threadIdx.x & 3;
    int g = threadIdx.x >> 2;
    int gw = blockIdx.x * 64 + g;
    if (gw >= N) return;
    int wl0 = (threadIdx.x & 63) - li;
    int col = ch * 16 + li * 4;

    float4 acc = make_float4(0.f, 0.f, 0.f, 0.f);
    int num = cnt[gw];
    int start = offs[gw];
    int base = 0;
    for (; base + 4 <= num; base += 4) {
        int sv = __builtin_nontemporal_load(&csr_src[start + base + li]);
        int s0 = __shfl(sv, wl0 + 0);
        int s1 = __shfl(sv, wl0 + 1);
        int s2 = __shfl(sv, wl0 + 2);
        int s3 = __shfl(sv, wl0 + 3);
        ushort4 a0 = *(const ushort4*)&T[(size_t)s0 * 128 + col];
        ushort4 a1 = *(const ushort4*)&T[(size_t)s1 * 128 + col];
        ushort4 a2 = *(const ushort4*)&T[(size_t)s2 * 128 + col];
        ushort4 a3 = *(const ushort4*)&T[(size_t)s3 * 128 + col];
        acc.x += bf2f(a0.x) + bf2f(a1.x) + bf2f(a2.x) + bf2f(a3.x);
        acc.y += bf2f(a0.y) + bf2f(a1.y) + bf2f(a2.y) + bf2f(a3.y);
        acc.z += bf2f(a0.z) + bf2f(a1.z) + bf2f(a2.z) + bf2f(a3.z);
        acc.w += bf2f(a0.w) + bf2f(a1.w) + bf2f(a2.w) + bf2f(a3.w);
    }
    if (base < num) {
        int sv = 0;
        if (base + li < num) sv = __builtin_nontemporal_load(&csr_src[start + base + li]);
        int m = num - base;
        for (int j = 0; j < m; j++) {
            int s = __shfl(sv, wl0 + j);
            ushort4 a = *(const ushort4*)&T[(size_t)s * 128 + col];
            acc.x += bf2f(a.x); acc.y += bf2f(a.y);
            acc.z += bf2f(a.z); acc.w += bf2f(a.w);
        }
    }
    float di = dinv[gw];
    ushort4 ts = *(const ushort4*)&T[(size_t)gw * 128 + col];
    float4 bb = *(const float4*)&bias[col];
    f32x4 o;
    o.x = di * (acc.x + bf2f(ts.x)) + bb.x;
    o.y = di * (acc.y + bf2f(ts.y)) + bb.y;
    o.z = di * (acc.z + bf2f(ts.z)) + bb.z;
    o.w = di * (acc.w + bf2f(ts.w)) + bb.w;
    if (RELU) {
        o.x = fmaxf(o.x, 0.f); o.y = fmaxf(o.y, 0.f);
        o.z = fmaxf(o.z, 0.f); o.w = fmaxf(o.w, 0.f);
    }
    __builtin_nontemporal_store(o, (f32x4*)&H[(size_t)gw * 128 + col]);
}

// ------- monolithic aggregation (C=64) — CONTROL, unchanged from R9 -------
template <int C, bool RELU>
__global__ __launch_bounds__(256) void k_aggregate(const unsigned short* __restrict__ T,
                                                   const int* __restrict__ offs,
                                                   const int* __restrict__ cnt, const int* __restrict__ csr_src,
                                                   const float* __restrict__ dinv,
                                                   const float* __restrict__ bias, float* __restrict__ H, int N) {
    constexpr int LANES = C / 4;
    constexpr int NPB = 256 / LANES;
    int li = threadIdx.x & (LANES - 1);
    int g = threadIdx.x / LANES;
    int gw = blockIdx.x * NPB + g;
    if (gw >= N) return;
    int wl0 = (threadIdx.x & 63) - li;

    float4 acc = make_float4(0.f, 0.f, 0.f, 0.f);
    int num = cnt[gw];
    int start = offs[gw];
    for (int base = 0; base < num; base += LANES) {
        int sv = 0;
        if (base + li < num) sv = csr_src[start + base + li];
        int m = num - base;
        if (m > LANES) m = LANES;
        int j = 0;
        for (; j + 4 <= m; j += 4) {
            int s0 = __shfl(sv, wl0 + j + 0);
            int s1 = __shfl(sv, wl0 + j + 1);
            int s2 = __shfl(sv, wl0 + j + 2);
            int s3 = __shfl(sv, wl0 + j + 3);
            ushort4 a0 = *(const ushort4*)&T[(size_t)s0 * C + li * 4];
            ushort4 a1 = *(const ushort4*)&T[(size_t)s1 * C + li * 4];
            ushort4 a2 = *(const ushort4*)&T[(size_t)s2 * C + li * 4];
            ushort4 a3 = *(const ushort4*)&T[(size_t)s3 * C + li * 4];
            acc.x += bf2f(a0.x) + bf2f(a1.x) + bf2f(a2.x) + bf2f(a3.x);
            acc.y += bf2f(a0.y) + bf2f(a1.y) + bf2f(a2.y) + bf2f(a3.y);
            acc.z += bf2f(a0.z) + bf2f(a1.z) + bf2f(a2.z) + bf2f(a3.z);
            acc.w += bf2f(a0.w) + bf2f(a1.w) + bf2f(a2.w) + bf2f(a3.w);
        }
        for (; j < m; j++) {
            int s = __shfl(sv, wl0 + j);
            ushort4 a = *(const ushort4*)&T[(size_t)s * C + li * 4];
            acc.x += bf2f(a.x); acc.y += bf2f(a.y);
            acc.z += bf2f(a.z); acc.w += bf2f(a.w);
        }
    }
    float di = dinv[gw];
    ushort4 tsu = *(const ushort4*)&T[(size_t)gw * C + li * 4];
    float4 bb = *(const float4*)&bias[li * 4];
    float4 o;
    o.x = di * (acc.x + bf2f(tsu.x)) + bb.x;
    o.y = di * (acc.y + bf2f(tsu.y)) + bb.y;
    o.z = di * (acc.z + bf2f(tsu.z)) + bb.z;
    o.w = di * (acc.w + bf2f(tsu.w)) + bb.w;
    if (RELU) {
        o.x = fmaxf(o.x, 0.f); o.y = fmaxf(o.y, 0.f);
        o.z = fmaxf(o.z, 0.f); o.w = fmaxf(o.w, 0.f);
    }
    *(float4*)&H[(size_t)gw * C + li * 4] = o;
}

// ------- chunked per-edge MLP: partial y over a 16-col slice of Z -------
// 4 lanes/edge; pass FIRST inits out with b2, later passes accumulate.
template <bool FIRST>
__global__ __launch_bounds__(256) void k_emlp16(const int* __restrict__ ei, int E,
                                                const unsigned short* __restrict__ Z,
                                                const float* __restrict__ b1,
                                                const float* __restrict__ w2, const float* __restrict__ b2,
                                                float* __restrict__ out, const int* __restrict__ flag,
                                                int ch) {
    int is32 = *flag;
    long long t = (long long)blockIdx.x * 256 + threadIdx.x;
    int e = (int)(t >> 2);
    int li = (int)(t & 3);
    if (e >= E) return;
    int s = edge_at(ei, e, is32);
    int d = edge_at(ei, (long long)E + e, is32);
    int col = ch * 16 + li * 4;
    ushort4 zsu = *(const ushort4*)&Z[(size_t)s * 64 + col];
    ushort4 zdu = *(const ushort4*)&Z[(size_t)d * 64 + col];
    float4 bb = *(const float4*)&b1[col];
    float4 u;
    u.x = fmaxf(0.f, 0.5f * (bf2f(zsu.x) + bf2f(zdu.x)) + bb.x);
    u.y = fmaxf(0.f, 0.5f * (bf2f(zsu.y) + bf2f(zdu.y)) + bb.y);
    u.z = fmaxf(0.f, 0.5f * (bf2f(zsu.z) + bf2f(zdu.z)) + bb.z);
    u.w = fmaxf(0.f, 0.5f * (bf2f(zsu.w) + bf2f(zdu.w)) + bb.w);
    float4 wa = *(const float4*)&w2[col * 2];      // rows col, col+1 (both out cols)
    float4 wb = *(const float4*)&w2[col * 2 + 4];  // rows col+2, col+3
    float y0 = u.x * wa.x + u.y * wa.z + u.z * wb.x + u.w * wb.z;
    float y1 = u.x * wa.y + u.y * wa.w + u.z * wb.y + u.w * wb.w;
#pragma unroll
    for (int m = 1; m < 4; m <<= 1) {
        y0 += __shfl_xor(y0, m);
        y1 += __shfl_xor(y1, m);
    }
    if (FIRST) {
        if (li == 0) out[(size_t)e * 2 + 0] = y0 + b2[0];
        else if (li == 1) out[(size_t)e * 2 + 1] = y1 + b2[1];
    } else {
        if (li == 0) out[(size_t)e * 2 + 0] += y0;
        else if (li == 1) out[(size_t)e * 2 + 1] += y1;
    }
}

extern "C" void kernel_launch(void* const* d_in, const int* in_sizes, int n_in,
                              void* d_out, int out_size, void* d_ws, size_t ws_size,
                              hipStream_t stream) {
    const float* x = (const float*)d_in[0];
    const int* ei = (const int*)d_in[1];
    const float* W0 = (const float*)d_in[2];
    const float* b0 = (const float*)d_in[3];
    const float* W1 = (const float*)d_in[4];
    const float* b1 = (const float*)d_in[5];
    const float* W2 = (const float*)d_in[6];
    const float* b2 = (const float*)d_in[7];
    const float* mw1 = (const float*)d_in[8];
    const float* mb1 = (const float*)d_in[9];
    const float* mw2 = (const float*)d_in[10];
    const float* mb2 = (const float*)d_in[11];
    float* out = (float*)d_out;

    int N = in_sizes[0] / 128;
    int E = in_sizes[1] / 2;

    char* p = (char*)d_ws;
    auto alloc = [&](size_t bytes) {
        char* q = p;
        p += (bytes + 255) & ~size_t(255);
        return q;
    };
    float* bufF = (float*)alloc((size_t)N * 128 * 4);
    unsigned short* bufH = (unsigned short*)alloc((size_t)N * 128 * 2);
    int* cnt = (int*)alloc((size_t)N * 4);
    int* offs = (int*)alloc((size_t)N * 4);
    float* dinv = (float*)alloc((size_t)N * 4);
    int* csr_src = (int*)alloc((size_t)E * 4);
    int* rank = (int*)alloc((size_t)E * 4);
    int* bsums = (int*)alloc(4096);
    int* flag = (int*)alloc(256);

    hipMemsetAsync(cnt, 0, (size_t)N * 4, stream);
    hipMemsetAsync(flag, 0, 4, stream);

    int gE = (E + 255) / 256;
    int gN = (N + 255) / 256;
    int nchunks = (2 * E) / 4;
    k_detect<<<1024, 256, 0, stream>>>((const int4*)ei, nchunks, flag);
    k_count<<<gE, 256, 0, stream>>>(ei, E, cnt, rank, flag);
    int nb = (N + 1023) / 1024;
    k_scan_local<<<nb, 256, 0, stream>>>(cnt, N, offs, bsums);
    k_scan_bsums<<<1, 1, 0, stream>>>(bsums, nb);
    k_scan_add<<<gN, 256, 0, stream>>>(offs, bsums, cnt, dinv, N);
    k_fill<<<gE, 256, 0, stream>>>(ei, E, offs, rank, csr_src, flag);

    int gG = (N + 63) / 64;
    int gC = (N + 63) / 64;     // 64 nodes/block for chunked aggregate
    int gA64 = (N + 15) / 16;   // control kernel

    // layer 0
    k_gemm<128, 128, true><<<gG, 256, 0, stream>>>(x, W0, bufH, N, dinv);
    for (int ch = 0; ch < 8; ch++)
        k_agg16<true><<<gC, 256, 0, stream>>>(bufH, offs, cnt, csr_src, dinv, b0, bufF, N, ch);
    // layer 1
    k_gemm<128, 128, true><<<gG, 256, 0, stream>>>(bufF, W1, bufH, N, dinv);
    for (int ch = 0; ch < 8; ch++)
        k_agg16<true><<<gC, 256, 0, stream>>>(bufH, offs, cnt, csr_src, dinv, b1, bufF, N, ch);
    // layer 2 (no relu) — CONTROL: monolithic
    k_gemm<128, 64, true><<<gG, 256, 0, stream>>>(bufF, W2, bufH, N, dinv);
    k_aggregate<64, false><<<gA64, 256, 0, stream>>>(bufH, offs, cnt, csr_src, dinv, b2, bufF, N);
    // z = h2 @ mlp_w1 (bf16 out)
    k_gemm<64, 64, false><<<gG, 256, 0, stream>>>(bufF, mw1, bufH, N, nullptr);

    // edge MLP: 4 chunked passes, partial dot accumulated in out
    long long totalT = (long long)E * 4;
    int gM = (int)((totalT + 255) / 256);
    k_emlp16<true><<<gM, 256, 0, stream>>>(ei, E, bufH, mb1, mw2, mb2, out, flag, 0);
    for (int ch = 1; ch < 4; ch++)
        k_emlp16<false><<<gM, 256, 0, stream>>>(ei, E, bufH, mb1, mw2, mb2, out, flag, ch);
}

// Round 12
// 574.499 us; speedup vs baseline: 2.0684x; 2.0684x over previous
//
#include <hip/hip_runtime.h>

// GCN: N=100000, E=1600000, C=128/128/64.
// R2: single-stream CSR fill. R4: gemm unroll/VGPR fix. R5: nt scatter FAILED.
// R7: rank-from-count (atomic-free fill). R8: gather ILP only -4% (plateau).
// R9: bf16 gather tables -> 688us. R10/R11: feature-chunked passes FAILED
//     (+500us: per-pass csr re-stream + 32B slices) -> REVERTED to monolithic.
// R12: all 4 GEMMs -> MFMA bf16 (16x16x32). Vector fp32 gemm was 73us at 45%
//     VALU / 31% occ (latency-bound); MFMA is 16x compute rate -> memory-bound.
//     W pre-packed to B-fragment layout; A staged bf16 in LDS (+8 pad);
//     aggregates output bf16 H directly (same numerics as convert-at-GEMM).

typedef unsigned short u16;
typedef short bf16x8 __attribute__((ext_vector_type(8)));
typedef float f32x4 __attribute__((ext_vector_type(4)));

__device__ __forceinline__ int edge_at(const int* __restrict__ ei, long long idx, int is32) {
    return is32 ? ei[idx] : ei[2 * idx];
}

__device__ __forceinline__ u16 f2bf(float f) {
    unsigned int u = __float_as_uint(f);
    u += 0x7FFFu + ((u >> 16) & 1u);
    return (u16)(u >> 16);
}
__device__ __forceinline__ float bf2f(u16 h) {
    return __uint_as_float(((unsigned int)h) << 16);
}

// Wave-reduced detect: OR odd words locally, <=1 atomic per wave.
__global__ __launch_bounds__(256) void k_detect(const int4* __restrict__ ei4, int nchunks,
                                                int* __restrict__ flag) {
    int acc = 0;
    for (int i = blockIdx.x * 256 + threadIdx.x; i < nchunks; i += gridDim.x * 256) {
        int4 v = ei4[i];
        acc |= v.y | v.w;
    }
    if (__any(acc != 0)) {
        if ((threadIdx.x & 63) == 0) atomicOr(flag, 1);
    }
}

// Count degrees AND record per-edge rank among same-dst edges.
__global__ __launch_bounds__(256) void k_count(const int* __restrict__ ei, int E, int* __restrict__ cnt,
                                               int* __restrict__ rank, const int* __restrict__ flag) {
    int is32 = *flag;
    int e = blockIdx.x * 256 + threadIdx.x;
    if (e < E) {
        int d = edge_at(ei, (long long)E + e, is32);
        rank[e] = atomicAdd(&cnt[d], 1);
    }
}

__global__ __launch_bounds__(256) void k_scan_local(const int* __restrict__ cnt, int N,
                                                    int* __restrict__ offs, int* __restrict__ bsums) {
    __shared__ int wsum[4];
    int t = threadIdx.x;
    int lane = t & 63, wid = t >> 6;
    int gbase = blockIdx.x * 1024 + t * 4;
    int v0 = 0, v1 = 0, v2 = 0, v3 = 0;
    if (gbase + 0 < N) v0 = cnt[gbase + 0];
    if (gbase + 1 < N) v1 = cnt[gbase + 1];
    if (gbase + 2 < N) v2 = cnt[gbase + 2];
    if (gbase + 3 < N) v3 = cnt[gbase + 3];
    int tot = v0 + v1 + v2 + v3;
    int x = tot;
#pragma unroll
    for (int d = 1; d < 64; d <<= 1) {
        int y = __shfl_up(x, d);
        if (lane >= d) x += y;
    }
    if (lane == 63) wsum[wid] = x;
    __syncthreads();
    int wbase = 0;
#pragma unroll
    for (int w = 0; w < 4; w++)
        if (w < wid) wbase += wsum[w];
    int ex = wbase + x - tot;
    if (gbase + 0 < N) offs[gbase + 0] = ex;
    if (gbase + 1 < N) offs[gbase + 1] = ex + v0;
    if (gbase + 2 < N) offs[gbase + 2] = ex + v0 + v1;
    if (gbase + 3 < N) offs[gbase + 3] = ex + v0 + v1 + v2;
    if (t == 255) bsums[blockIdx.x] = wbase + x;
}

__global__ void k_scan_bsums(int* __restrict__ bsums, int nb) {
    int run = 0;
    for (int i = 0; i < nb; i++) {
        int v = bsums[i];
        bsums[i] = run;
        run += v;
    }
}

__global__ __launch_bounds__(256) void k_scan_add(int* __restrict__ offs, const int* __restrict__ bsums,
                                                  const int* __restrict__ cnt, float* __restrict__ dinv, int N) {
    int i = blockIdx.x * 256 + threadIdx.x;
    if (i < N) {
        offs[i] += bsums[i >> 10];
        dinv[i] = rsqrtf((float)(cnt[i] + 1));
    }
}

// Atomic-free scatter: pos = offs_excl[d] + rank[e].
__global__ __launch_bounds__(256) void k_fill(const int* __restrict__ ei, int E,
                                              const int* __restrict__ offs, const int* __restrict__ rank,
                                              int* __restrict__ csr_src, const int* __restrict__ flag) {
    int is32 = *flag;
    int e = blockIdx.x * 256 + threadIdx.x;
    if (e < E) {
        int s = edge_at(ei, e, is32);
        int d = edge_at(ei, (long long)E + e, is32);
        int pos = offs[d] + rank[e];
        csr_src[pos] = s;
    }
}

// ---- pack fp32 W[CIN][COUT] into MFMA B-fragment layout (bf16) ----
// Wpack[((ct*KS + ks)*64 + lane)*8 + j] = W[ks*32 + (lane>>4)*8 + j][ct*16 + (lane&15)]
template <int CIN, int COUT>
__global__ __launch_bounds__(256) void k_packW(const float* __restrict__ W, u16* __restrict__ P) {
    constexpr int KS = CIN / 32;
    int idx = blockIdx.x * 256 + threadIdx.x;
    int total = (COUT / 16) * KS * 64;
    if (idx >= total) return;
    int l = idx & 63;
    int t = idx >> 6;
    int ks = t % KS, ct = t / KS;
    int c = ct * 16 + (l & 15);
    int k0 = ks * 32 + (l >> 4) * 8;
    u16 o[8];
#pragma unroll
    for (int j = 0; j < 8; j++) o[j] = f2bf(W[(size_t)(k0 + j) * COUT + c]);
    *(ushort4*)&P[(size_t)idx * 8 + 0] = make_ushort4(o[0], o[1], o[2], o[3]);
    *(ushort4*)&P[(size_t)idx * 8 + 4] = make_ushort4(o[4], o[5], o[6], o[7]);
}

// ---- MFMA GEMM: Ybf16[N,COUT] = f2bf( rscale? ⊙ (X[N,CIN] @ W) ) ----
// 256 thr = 4 waves; 64-row tile (16 rows/wave), full COUT width.
// A frag: lane holds A[row=l&15][k = ks*32 + (l>>4)*8 + j] from LDS (b128).
// B frag: from pre-packed Wpack (coalesced 16B/lane).
// D frag (m89-verified): col=lane&15, row=(lane>>4)*4+reg.
template <int CIN, int COUT, bool RSCALE, bool AFP32>
__global__ __launch_bounds__(256) void k_gemm_mfma(const void* __restrict__ Xv,
                                                   const u16* __restrict__ Wp,
                                                   u16* __restrict__ Y, int N,
                                                   const float* __restrict__ rscale) {
    constexpr int KS = CIN / 32;
    constexpr int CT = COUT / 16;
    constexpr int LDA = CIN + 8;  // bf16 elems; +8 keeps 16B alignment, shifts banks
    __shared__ u16 As[64 * LDA];
    int t = threadIdx.x;
    int r0 = blockIdx.x * 64;

    if (AFP32) {
        const float* X = (const float*)Xv;
        for (int i = t * 4; i < 64 * CIN; i += 1024) {
            int row = i / CIN, col = i % CIN;
            float4 v = make_float4(0.f, 0.f, 0.f, 0.f);
            int grow = r0 + row;
            if (grow < N) v = *(const float4*)&X[(size_t)grow * CIN + col];
            *(ushort4*)&As[row * LDA + col] = make_ushort4(f2bf(v.x), f2bf(v.y), f2bf(v.z), f2bf(v.w));
        }
    } else {
        const u16* X = (const u16*)Xv;
        for (int i = t * 8; i < 64 * CIN; i += 2048) {
            int row = i / CIN, col = i % CIN;
            uint4 v = make_uint4(0, 0, 0, 0);
            int grow = r0 + row;
            if (grow < N) v = *(const uint4*)&X[(size_t)grow * CIN + col];
            *(uint4*)&As[row * LDA + col] = v;
        }
    }
    __syncthreads();

    int w = t >> 6;
    int l = t & 63;
    int lr = l & 15;   // A-row within tile / D-col
    int lk = l >> 4;   // k-group
    f32x4 acc[CT];
#pragma unroll
    for (int i = 0; i < CT; i++) {
        f32x4 z = {0.f, 0.f, 0.f, 0.f};
        acc[i] = z;
    }
    const u16* arow = &As[(w * 16 + lr) * LDA + lk * 8];
#pragma unroll
    for (int ks = 0; ks < KS; ks++) {
        bf16x8 a = *(const bf16x8*)&arow[ks * 32];
#pragma unroll
        for (int ct = 0; ct < CT; ct++) {
            bf16x8 b = *(const bf16x8*)&Wp[((size_t)(ct * KS + ks) * 64 + l) * 8];
            acc[ct] = __builtin_amdgcn_mfma_f32_16x16x32_bf16(a, b, acc[ct], 0, 0, 0);
        }
    }
#pragma unroll
    for (int i = 0; i < 4; i++) {
        int grow = r0 + w * 16 + lk * 4 + i;
        if (grow < N) {
            float s = 1.f;
            if (RSCALE) s = rscale[grow];
#pragma unroll
            for (int ct = 0; ct < CT; ct++) {
                Y[(size_t)grow * COUT + ct * 16 + lr] = f2bf(acc[ct][i] * s);
            }
        }
    }
}

// ------- aggregation (monolithic, R9-validated): H = relu?(dinv*(sum+self)+b), bf16 out -------
template <int C, bool RELU>
__global__ __launch_bounds__(256) void k_aggregate(const u16* __restrict__ T,
                                                   const int* __restrict__ offs,
                                                   const int* __restrict__ cnt, const int* __restrict__ csr_src,
                                                   const float* __restrict__ dinv,
                                                   const float* __restrict__ bias, u16* __restrict__ H, int N) {
    constexpr int LANES = C / 4;
    constexpr int NPB = 256 / LANES;
    int li = threadIdx.x & (LANES - 1);
    int g = threadIdx.x / LANES;
    int gw = blockIdx.x * NPB + g;
    if (gw >= N) return;
    int wl0 = (threadIdx.x & 63) - li;

    float4 acc = make_float4(0.f, 0.f, 0.f, 0.f);
    int num = cnt[gw];
    int start = offs[gw];
    for (int base = 0; base < num; base += LANES) {
        int sv = 0;
        if (base + li < num) sv = csr_src[start + base + li];
        int m = num - base;
        if (m > LANES) m = LANES;
        int j = 0;
        for (; j + 4 <= m; j += 4) {
            int s0 = __shfl(sv, wl0 + j + 0);
            int s1 = __shfl(sv, wl0 + j + 1);
            int s2 = __shfl(sv, wl0 + j + 2);
            int s3 = __shfl(sv, wl0 + j + 3);
            ushort4 a0 = *(const ushort4*)&T[(size_t)s0 * C + li * 4];
            ushort4 a1 = *(const ushort4*)&T[(size_t)s1 * C + li * 4];
            ushort4 a2 = *(const ushort4*)&T[(size_t)s2 * C + li * 4];
            ushort4 a3 = *(const ushort4*)&T[(size_t)s3 * C + li * 4];
            acc.x += bf2f(a0.x) + bf2f(a1.x) + bf2f(a2.x) + bf2f(a3.x);
            acc.y += bf2f(a0.y) + bf2f(a1.y) + bf2f(a2.y) + bf2f(a3.y);
            acc.z += bf2f(a0.z) + bf2f(a1.z) + bf2f(a2.z) + bf2f(a3.z);
            acc.w += bf2f(a0.w) + bf2f(a1.w) + bf2f(a2.w) + bf2f(a3.w);
        }
        for (; j < m; j++) {
            int s = __shfl(sv, wl0 + j);
            ushort4 a = *(const ushort4*)&T[(size_t)s * C + li * 4];
            acc.x += bf2f(a.x); acc.y += bf2f(a.y);
            acc.z += bf2f(a.z); acc.w += bf2f(a.w);
        }
    }
    float di = dinv[gw];
    ushort4 tsu = *(const ushort4*)&T[(size_t)gw * C + li * 4];
    float4 bb = *(const float4*)&bias[li * 4];
    float ox = di * (acc.x + bf2f(tsu.x)) + bb.x;
    float oy = di * (acc.y + bf2f(tsu.y)) + bb.y;
    float oz = di * (acc.z + bf2f(tsu.z)) + bb.z;
    float ow = di * (acc.w + bf2f(tsu.w)) + bb.w;
    if (RELU) {
        ox = fmaxf(ox, 0.f); oy = fmaxf(oy, 0.f);
        oz = fmaxf(oz, 0.f); ow = fmaxf(ow, 0.f);
    }
    *(ushort4*)&H[(size_t)gw * C + li * 4] = make_ushort4(f2bf(ox), f2bf(oy), f2bf(oz), f2bf(ow));
}

// ------- per-edge MLP (monolithic, R9-validated): y = relu(0.5*(z_s+z_d)+b1) @ w2 + b2 -------
__global__ __launch_bounds__(256) void k_edge_mlp(const int* __restrict__ ei, int E,
                                                  const u16* __restrict__ Z,
                                                  const float* __restrict__ b1,
                                                  const float* __restrict__ w2, const float* __restrict__ b2,
                                                  float* __restrict__ out, const int* __restrict__ flag) {
    int is32 = *flag;
    long long t = (long long)blockIdx.x * 256 + threadIdx.x;
    int e = (int)(t >> 4);
    int l = (int)(t & 15);
    if (e >= E) return;
    int s = edge_at(ei, e, is32);
    int d = edge_at(ei, (long long)E + e, is32);
    ushort4 zsu = *(const ushort4*)&Z[(size_t)s * 64 + l * 4];
    ushort4 zdu = *(const ushort4*)&Z[(size_t)d * 64 + l * 4];
    float4 bb = *(const float4*)&b1[l * 4];
    float4 u;
    u.x = fmaxf(0.f, 0.5f * (bf2f(zsu.x) + bf2f(zdu.x)) + bb.x);
    u.y = fmaxf(0.f, 0.5f * (bf2f(zsu.y) + bf2f(zdu.y)) + bb.y);
    u.z = fmaxf(0.f, 0.5f * (bf2f(zsu.z) + bf2f(zdu.z)) + bb.z);
    u.w = fmaxf(0.f, 0.5f * (bf2f(zsu.w) + bf2f(zdu.w)) + bb.w);
    float4 wa = *(const float4*)&w2[l * 8];
    float4 wb = *(const float4*)&w2[l * 8 + 4];
    float y0 = u.x * wa.x + u.y * wa.z + u.z * wb.x + u.w * wb.z;
    float y1 = u.x * wa.y + u.y * wa.w + u.z * wb.y + u.w * wb.w;
#pragma unroll
    for (int m = 1; m < 16; m <<= 1) {
        y0 += __shfl_xor(y0, m);
        y1 += __shfl_xor(y1, m);
    }
    if (l == 0) out[(size_t)e * 2 + 0] = y0 + b2[0];
    else if (l == 1) out[(size_t)e * 2 + 1] = y1 + b2[1];
}

extern "C" void kernel_launch(void* const* d_in, const int* in_sizes, int n_in,
                              void* d_out, int out_size, void* d_ws, size_t ws_size,
                              hipStream_t stream) {
    const float* x = (const float*)d_in[0];
    const int* ei = (const int*)d_in[1];
    const float* W0 = (const float*)d_in[2];
    const float* b0 = (const float*)d_in[3];
    const float* W1 = (const float*)d_in[4];
    const float* b1 = (const float*)d_in[5];
    const float* W2 = (const float*)d_in[6];
    const float* b2 = (const float*)d_in[7];
    const float* mw1 = (const float*)d_in[8];
    const float* mb1 = (const float*)d_in[9];
    const float* mw2 = (const float*)d_in[10];
    const float* mb2 = (const float*)d_in[11];
    float* out = (float*)d_out;

    int N = in_sizes[0] / 128;
    int E = in_sizes[1] / 2;

    char* p = (char*)d_ws;
    auto alloc = [&](size_t bytes) {
        char* q = p;
        p += (bytes + 255) & ~size_t(255);
        return q;
    };
    u16* bufA = (u16*)alloc((size_t)N * 128 * 2);  // GEMM outputs (T'/Z)
    u16* bufB = (u16*)alloc((size_t)N * 128 * 2);  // aggregate outputs (H)
    int* cnt = (int*)alloc((size_t)N * 4);
    int* offs = (int*)alloc((size_t)N * 4);
    float* dinv = (float*)alloc((size_t)N * 4);
    int* csr_src = (int*)alloc((size_t)E * 4);
    int* rank = (int*)alloc((size_t)E * 4);
    int* bsums = (int*)alloc(4096);
    int* flag = (int*)alloc(256);
    u16* pW0 = (u16*)alloc(128 * 128 * 2);
    u16* pW1 = (u16*)alloc(128 * 128 * 2);
    u16* pW2 = (u16*)alloc(128 * 64 * 2);
    u16* pZ = (u16*)alloc(64 * 64 * 2);

    hipMemsetAsync(cnt, 0, (size_t)N * 4, stream);
    hipMemsetAsync(flag, 0, 4, stream);

    int gE = (E + 255) / 256;
    int gN = (N + 255) / 256;
    int nchunks = (2 * E) / 4;
    k_detect<<<1024, 256, 0, stream>>>((const int4*)ei, nchunks, flag);
    k_packW<128, 128><<<8, 256, 0, stream>>>(W0, pW0);
    k_packW<128, 128><<<8, 256, 0, stream>>>(W1, pW1);
    k_packW<128, 64><<<4, 256, 0, stream>>>(W2, pW2);
    k_packW<64, 64><<<2, 256, 0, stream>>>(mw1, pZ);
    k_count<<<gE, 256, 0, stream>>>(ei, E, cnt, rank, flag);
    int nb = (N + 1023) / 1024;
    k_scan_local<<<nb, 256, 0, stream>>>(cnt, N, offs, bsums);
    k_scan_bsums<<<1, 1, 0, stream>>>(bsums, nb);
    k_scan_add<<<gN, 256, 0, stream>>>(offs, bsums, cnt, dinv, N);
    k_fill<<<gE, 256, 0, stream>>>(ei, E, offs, rank, csr_src, flag);

    int gG = (N + 63) / 64;
    int gA128 = (N + 7) / 8;
    int gA64 = (N + 15) / 16;

    // layer 0: T' = bf16(dinv ⊙ (x@W0)); h0 = bf16(relu(dinv ⊙ (agg+self) + b0))
    k_gemm_mfma<128, 128, true, true><<<gG, 256, 0, stream>>>(x, pW0, bufA, N, dinv);
    k_aggregate<128, true><<<gA128, 256, 0, stream>>>(bufA, offs, cnt, csr_src, dinv, b0, bufB, N);
    // layer 1
    k_gemm_mfma<128, 128, true, false><<<gG, 256, 0, stream>>>(bufB, pW1, bufA, N, dinv);
    k_aggregate<128, true><<<gA128, 256, 0, stream>>>(bufA, offs, cnt, csr_src, dinv, b1, bufB, N);
    // layer 2 (no relu)
    k_gemm_mfma<128, 64, true, false><<<gG, 256, 0, stream>>>(bufB, pW2, bufA, N, dinv);
    k_aggregate<64, false><<<gA64, 256, 0, stream>>>(bufA, offs, cnt, csr_src, dinv, b2, bufB, N);
    // z = h2 @ mlp_w1
    k_gemm_mfma<64, 64, false, false><<<gG, 256, 0, stream>>>(bufB, pZ, bufA, N, nullptr);

    long long totalT = (long long)E * 16;
    int gM = (int)((totalT + 255) / 256);
    k_edge_mlp<<<gM, 256, 0, stream>>>(ei, E, bufA, mb1, mw2, mb2, out, flag);
}